// Round 5
// baseline (268.732 us; speedup 1.0000x reference)
//
#include <hip/hip_runtime.h>
#include <hip/hip_bf16.h>

// ============================================================================
// ROUND 5: DECOMPOSITION PROBE (intentional 4x work, numerically identical).
// Purpose: harness dur_us (~170us) was invariant under a major kernel
// restructure (r1->r4), suggesting it is dominated by harness poison fills
// (512MiB fills @ ~83us visible in rocprof) and that the kernel itself is only
// ~25us — but the kernel's dispatch is below the top-5 visibility cutoff
// (79.8us). Running the identical pipeline 4x pushes our dispatch to
// ~85-110us -> visible in top-5 WITH its own counters, and
// dur_us_new - dur_us_old ≈ 3 x kernel_time gives the decomposition.
// Correctness: all 4 passes compute and store bit-identical values (z = 0.0f
// laundered through asm so the compiler must recompute; x+0.0f is exact).
// ============================================================================

#define BB 8
#define NN 4096
#define MM 1024
#define CC 10

#define ROWS_PER_BLOCK 32
#define BLOCKS_PER_BATCH (NN / ROWS_PER_BLOCK)   // 128 -> grid = 1024

#define NPASS 4

__device__ __forceinline__ float fast_rcp(float x) {
    float r;
    asm("v_rcp_f32 %0, %1" : "=v"(r) : "v"(x));
    return r;
}

__global__ __launch_bounds__(256, 4)
void transfusion_cost_kernel(const float* __restrict__ bboxes,      // [B,N,7]
                             const float* __restrict__ gt_bboxes,   // [B,M,7]
                             const float* __restrict__ cls_pred,    // [B,N,C]
                             const int*   __restrict__ gt_labels,   // [B,M]
                             float* __restrict__ out)               // [B,N,M]
{
    const int tid  = threadIdx.x;
    const int lane = tid & 63;
    const int wave = tid >> 6;

    const int b  = blockIdx.x / BLOCKS_PER_BATCH;
    const int n0 = (blockIdx.x % BLOCKS_PER_BATCH) * ROWS_PER_BLOCK;

    const float SCL = 0.25f / 108.0f;

    // ---- per-lane gt state: 4 consecutive m (pass-invariant, hoisted) ----
    const int m0 = wave * 256 + 4 * lane;
    const float* gtb = gt_bboxes + ((size_t)b * MM + m0) * 7;
    const int*   gtl = gt_labels + (size_t)b * MM + m0;

    float gx1[4], gy1[4], gx2[4], gy2[4], areaB[4], bxs[4], bys[4];
    int   lbl[4];
#pragma unroll
    for (int j = 0; j < 4; ++j) {
        const float* g = gtb + j * 7;
        const float x  = g[0];
        const float y  = g[1];
        const float dx = g[3];
        const float dy = g[4];
        const float x1 = x - 0.5f * dx, x2 = x + 0.5f * dx;
        const float y1 = y - 0.5f * dy, y2 = y + 0.5f * dy;
        gx1[j] = x1; gy1[j] = y1; gx2[j] = x2; gy2[j] = y2;
        areaB[j] = fmaxf(x2 - x1, 0.0f) * fmaxf(y2 - y1, 0.0f);
        bxs[j] = (x + 54.0f) * SCL;
        bys[j] = (y + 54.0f) * SCL;
        lbl[j] = gtl[j];
    }

    const int c = (lane < CC) ? lane : 0;
    const float* arow = bboxes   + ((size_t)b * NN + n0) * 7;
    const float* crow = cls_pred + ((size_t)b * NN + n0) * CC;
    float*       orow = out + ((size_t)b * NN + n0) * MM + m0;

    for (int pass = 0; pass < NPASS; ++pass) {
        // Laundered zero: compiler cannot prove z==0 -> must recompute the
        // full dataflow each pass. x + 0.0f is bit-exact (incl. -0.0 paths
        // here), so all passes store identical values.
        float z = 0.0f;
        asm volatile("" : "+v"(z));

#pragma unroll 2
        for (int r = 0; r < ROWS_PER_BLOCK; ++r) {
            const float* a = arow + r * 7;
            const float ax  = a[0] + z;
            const float ay  = a[1] + z;
            const float adx = a[3];
            const float ady = a[4];
            const float logit = crow[r * CC + c] + z;

            const float xa1 = ax - 0.5f * adx, xa2 = ax + 0.5f * adx;
            const float ya1 = ay - 0.5f * ady, ya2 = ay + 0.5f * ady;
            const float areaA = fmaxf(xa2 - xa1, 0.0f) * fmaxf(ya2 - ya1, 0.0f);
            const float axs = (ax + 54.0f) * SCL;
            const float ays = (ay + 54.0f) * SCL;

            const float p   = 1.0f / (1.0f + expf(-logit));
            const float omp = 1.0f - p;
            const float pos = -logf(p   + 1e-12f) * 0.25f * omp * omp;
            const float neg = -logf(omp + 1e-12f) * 0.75f * p * p;
            const float dval = (pos - neg) * 0.15f;

            float vv[4];
#pragma unroll
            for (int j = 0; j < 4; ++j) {
                const float ix1 = fmaxf(xa1, gx1[j]);
                const float iy1 = fmaxf(ya1, gy1[j]);
                const float ix2 = fminf(xa2, gx2[j]);
                const float iy2 = fminf(ya2, gy2[j]);
                const float iw  = fmaxf(ix2 - ix1, 0.0f);
                const float ih  = fmaxf(iy2 - iy1, 0.0f);
                const float inter = iw * ih;
                const float uni   = areaA + areaB[j] - inter;
                const float iou   = inter * fast_rcp(fmaxf(uni, 1e-6f));

                const float cls = __shfl(dval, lbl[j], 64);
                const float reg = fabsf(axs - bxs[j]) + fabsf(ays - bys[j]);

                vv[j] = cls + reg - 0.25f * iou;
            }

            *reinterpret_cast<float4*>(orow + (size_t)r * MM) =
                make_float4(vv[0], vv[1], vv[2], vv[3]);
        }

        // Keep every pass's stores live (no dead-store elimination across passes).
        asm volatile("" ::: "memory");
    }
}

extern "C" void kernel_launch(void* const* d_in, const int* in_sizes, int n_in,
                              void* d_out, int out_size, void* d_ws, size_t ws_size,
                              hipStream_t stream) {
    const float* bboxes    = (const float*)d_in[0];
    const float* gt_bboxes = (const float*)d_in[1];
    const float* cls_pred  = (const float*)d_in[2];
    const int*   gt_labels = (const int*)d_in[3];
    float* out = (float*)d_out;

    const int grid = BB * BLOCKS_PER_BATCH;   // 1024 blocks, 256 threads
    transfusion_cost_kernel<<<grid, 256, 0, stream>>>(bboxes, gt_bboxes, cls_pred,
                                                      gt_labels, out);
}

// Round 7
// 161.136 us; speedup vs baseline: 1.6677x; 1.6677x over previous
//
#include <hip/hip_runtime.h>
#include <hip/hip_bf16.h>

// ============================================================================
// ROUND 6 (resubmit; r6 bench failed on GPU acquisition):
// remove focal transcendentals from the hot loop.
// r5 probe showed: kernel is VALU-issue-bound (VALUBusy 84-85%, write BW only
// 40% of peak). Arithmetic: ~19 VALU/element IoU math ~9us/pass, but focal
// (expf + 2x logf, ~60-80 VALU via ocml) runs per-row PER-WAVE (4x redundant)
// ~ comparable issue cost. Fix: pre-kernel computes diff[B,N,C] (1.3 MB) once
// into d_ws; main kernel loads it (1 dword per row per wave) and keeps the
// 4x ds_bpermute label-gather. Numerics bit-identical (same expf/logf code,
// computed once). Also: grid 1024->2048 (8 blk/CU -> better store latency
// hiding), row unroll 4, pre-shifted bpermute addresses.
// ============================================================================

#define BB 8
#define NN 4096
#define MM 1024
#define CC 10

#define ROWS_PER_BLOCK 16
#define BLOCKS_PER_BATCH (NN / ROWS_PER_BLOCK)   // 256 -> grid = 2048

__device__ __forceinline__ float fast_rcp(float x) {
    float r;
    asm("v_rcp_f32 %0, %1" : "=v"(r) : "v"(x));
    return r;   // ~1 ulp; iou error ~1e-7, negligible vs absmax budget
}

__device__ __forceinline__ float focal_diff(float logit) {
    // EXACT same sequence as r1/r4 (absmax already validated against this).
    const float p   = 1.0f / (1.0f + expf(-logit));
    const float omp = 1.0f - p;
    const float pos = -logf(p   + 1e-12f) * 0.25f * omp * omp;
    const float neg = -logf(omp + 1e-12f) * 0.75f * p * p;
    return (pos - neg) * 0.15f;
}

// ---- pre-kernel: diff[b,n,c] for all B*N*C = 327,680 elements (~1.3 MB) ----
__global__ __launch_bounds__(256)
void focal_diff_kernel(const float* __restrict__ cls_pred, float* __restrict__ diff) {
    const int i = blockIdx.x * 256 + threadIdx.x;   // grid sized exactly
    diff[i] = focal_diff(cls_pred[i]);
}

// ---- main kernel ----
// USE_WS=1: dval loaded from precomputed diff. USE_WS=0: focal inline (fallback).
template <bool USE_WS>
__global__ __launch_bounds__(256, 8)
void transfusion_cost_kernel(const float* __restrict__ bboxes,      // [B,N,7]
                             const float* __restrict__ gt_bboxes,   // [B,M,7]
                             const float* __restrict__ cls_pred,    // [B,N,C]
                             const int*   __restrict__ gt_labels,   // [B,M]
                             const float* __restrict__ diff,        // [B,N,C] (ws)
                             float* __restrict__ out)               // [B,N,M]
{
    const int tid  = threadIdx.x;
    const int lane = tid & 63;
    const int wave = tid >> 6;                 // m-quarter index 0..3

    const int b  = blockIdx.x / BLOCKS_PER_BATCH;
    const int n0 = (blockIdx.x % BLOCKS_PER_BATCH) * ROWS_PER_BLOCK;

    const float SCL = 0.25f / 108.0f;          // REG_W folded into xy normalization

    // ---- per-lane gt state: 4 consecutive m, loaded once per block ----
    const int m0 = wave * 256 + 4 * lane;
    const float* gtb = gt_bboxes + ((size_t)b * MM + m0) * 7;
    const int*   gtl = gt_labels + (size_t)b * MM + m0;

    float gx1[4], gy1[4], gx2[4], gy2[4], areaB[4], bxs[4], bys[4];
    int   lbl4[4];                              // label byte-address for bpermute
#pragma unroll
    for (int j = 0; j < 4; ++j) {
        const float* g = gtb + j * 7;
        const float x  = g[0];
        const float y  = g[1];
        const float dx = g[3];
        const float dy = g[4];
        const float x1 = x - 0.5f * dx, x2 = x + 0.5f * dx;
        const float y1 = y - 0.5f * dy, y2 = y + 0.5f * dy;
        gx1[j] = x1; gy1[j] = y1; gx2[j] = x2; gy2[j] = y2;
        areaB[j] = fmaxf(x2 - x1, 0.0f) * fmaxf(y2 - y1, 0.0f);
        bxs[j] = (x + 54.0f) * SCL;
        bys[j] = (y + 54.0f) * SCL;
        lbl4[j] = gtl[j] << 2;
    }

    const int c = (lane < CC) ? lane : 0;      // focal channel this lane holds
    const float* arow = bboxes   + ((size_t)b * NN + n0) * 7;
    const float* crow = cls_pred + ((size_t)b * NN + n0) * CC;
    const float* drow = USE_WS ? diff + ((size_t)b * NN + n0) * CC : nullptr;
    float*       orow = out + ((size_t)b * NN + n0) * MM + m0;

    // ---- row loop ----
#pragma unroll 4
    for (int r = 0; r < ROWS_PER_BLOCK; ++r) {
        const float* a = arow + r * 7;
        const float ax  = a[0];
        const float ay  = a[1];
        const float adx = a[3];
        const float ady = a[4];

        float dval;
        if (USE_WS) {
            dval = drow[r * CC + c];           // 1 load replaces exp/log chain
        } else {
            dval = focal_diff(crow[r * CC + c]);
        }

        const float xa1 = ax - 0.5f * adx, xa2 = ax + 0.5f * adx;
        const float ya1 = ay - 0.5f * ady, ya2 = ay + 0.5f * ady;
        const float areaA = fmaxf(xa2 - xa1, 0.0f) * fmaxf(ya2 - ya1, 0.0f);
        const float axs = (ax + 54.0f) * SCL;
        const float ays = (ay + 54.0f) * SCL;

        const int dbits = __float_as_int(dval);

        float vv[4];
#pragma unroll
        for (int j = 0; j < 4; ++j) {
            const float ix1 = fmaxf(xa1, gx1[j]);
            const float iy1 = fmaxf(ya1, gy1[j]);
            const float ix2 = fminf(xa2, gx2[j]);
            const float iy2 = fminf(ya2, gy2[j]);
            const float iw  = fmaxf(ix2 - ix1, 0.0f);
            const float ih  = fmaxf(iy2 - iy1, 0.0f);
            const float inter = iw * ih;
            const float uni   = areaA + areaB[j] - inter;
            const float iou   = inter * fast_rcp(fmaxf(uni, 1e-6f));

            const float cls = __int_as_float(__builtin_amdgcn_ds_bpermute(lbl4[j], dbits));
            const float reg = fabsf(axs - bxs[j]) + fabsf(ays - bys[j]);

            vv[j] = cls + reg - 0.25f * iou;
        }

        *reinterpret_cast<float4*>(orow + (size_t)r * MM) =
            make_float4(vv[0], vv[1], vv[2], vv[3]);
    }
}

extern "C" void kernel_launch(void* const* d_in, const int* in_sizes, int n_in,
                              void* d_out, int out_size, void* d_ws, size_t ws_size,
                              hipStream_t stream) {
    const float* bboxes    = (const float*)d_in[0];
    const float* gt_bboxes = (const float*)d_in[1];
    const float* cls_pred  = (const float*)d_in[2];
    const int*   gt_labels = (const int*)d_in[3];
    float* out = (float*)d_out;

    const int grid = BB * BLOCKS_PER_BATCH;          // 2048 blocks, 256 threads
    const size_t diff_bytes = (size_t)BB * NN * CC * sizeof(float);  // 1.25 MiB

    if (ws_size >= diff_bytes) {
        float* diff = (float*)d_ws;
        focal_diff_kernel<<<(BB * NN * CC) / 256, 256, 0, stream>>>(cls_pred, diff);
        transfusion_cost_kernel<true><<<grid, 256, 0, stream>>>(
            bboxes, gt_bboxes, cls_pred, gt_labels, diff, out);
    } else {
        transfusion_cost_kernel<false><<<grid, 256, 0, stream>>>(
            bboxes, gt_bboxes, cls_pred, gt_labels, nullptr, out);
    }
}

// Round 15
// 154.590 us; speedup vs baseline: 1.7384x; 1.0423x over previous
//
#include <hip/hip_runtime.h>
#include <hip/hip_bf16.h>

// ============================================================================
// ROUND 15: revert nt stores (HARNESS-INCOMPATIBLE), keep both hoists.
// r14 finding: __builtin_nontemporal_store on d_out breaks the harness's
// re-poison/revalidate cycle — nt writes go around L2 while the poison fill
// leaves dirty L2 lines; post-timing readback saw stale data (absmax 0.32).
// Regular coherent dwordx4 stores restored. Remaining design (vs measured
// r7 = 161.1us): focal hoist (validated -9.2us) + row-math hoist (this
// round's single variable). If dur_us ~161 unchanged -> kernel is at the
// effective write floor (write 134MB + first-touch dirty-L2 interaction +
// ~100us fixed harness overhead) -> declare roofline.
// ============================================================================

#define BB 8
#define NN 4096
#define MM 1024
#define CC 10

#define ROWS_PER_BLOCK 16
#define BLOCKS_PER_BATCH (NN / ROWS_PER_BLOCK)   // 256 -> grid = 2048

typedef float vfloat4 __attribute__((ext_vector_type(4)));

__device__ __forceinline__ float fast_rcp(float x) {
    float r;
    asm("v_rcp_f32 %0, %1" : "=v"(r) : "v"(x));
    return r;   // ~1 ulp; iou error ~1e-7, negligible vs absmax budget
}

__device__ __forceinline__ float focal_diff(float logit) {
    // EXACT same sequence as r1..r7 (absmax validated against this).
    const float p   = 1.0f / (1.0f + expf(-logit));
    const float omp = 1.0f - p;
    const float pos = -logf(p   + 1e-12f) * 0.25f * omp * omp;
    const float neg = -logf(omp + 1e-12f) * 0.75f * p * p;
    return (pos - neg) * 0.15f;
}

// ---- pre-kernel 1: diff[b,n,c], B*N*C = 327,680 elems (~1.3 MB) ----
__global__ __launch_bounds__(256)
void focal_diff_kernel(const float* __restrict__ cls_pred, float* __restrict__ diff) {
    const int i = blockIdx.x * 256 + threadIdx.x;   // grid sized exactly
    diff[i] = focal_diff(cls_pred[i]);
}

// ---- pre-kernel 2: rowbuf[b*N+n][8] = {xa1,ya1,xa2,ya2, areaA,axs,ays,0} ----
__global__ __launch_bounds__(256)
void row_pre_kernel(const float* __restrict__ bboxes, float* __restrict__ rowbuf) {
    const int i = blockIdx.x * 256 + threadIdx.x;   // row index; grid = 32768/256
    const float ax  = bboxes[i * 7 + 0];
    const float ay  = bboxes[i * 7 + 1];
    const float adx = bboxes[i * 7 + 3];
    const float ady = bboxes[i * 7 + 4];
    const float SCL = 0.25f / 108.0f;
    const float xa1 = ax - 0.5f * adx, xa2 = ax + 0.5f * adx;
    const float ya1 = ay - 0.5f * ady, ya2 = ay + 0.5f * ady;
    const float areaA = fmaxf(xa2 - xa1, 0.0f) * fmaxf(ya2 - ya1, 0.0f);
    vfloat4* o = reinterpret_cast<vfloat4*>(rowbuf + (size_t)i * 8);
    o[0] = (vfloat4){xa1, ya1, xa2, ya2};
    o[1] = (vfloat4){areaA, (ax + 54.0f) * SCL, (ay + 54.0f) * SCL, 0.0f};
}

// ---- main kernel ----
template <bool USE_WS>
__global__ __launch_bounds__(256, 8)
void transfusion_cost_kernel(const float* __restrict__ bboxes,      // [B,N,7]
                             const float* __restrict__ gt_bboxes,   // [B,M,7]
                             const float* __restrict__ cls_pred,    // [B,N,C]
                             const int*   __restrict__ gt_labels,   // [B,M]
                             const float* __restrict__ diff,        // [B,N,C] (ws)
                             const float* __restrict__ rowbuf,      // [B,N,8] (ws)
                             float* __restrict__ out)               // [B,N,M]
{
    const int tid  = threadIdx.x;
    const int lane = tid & 63;
    const int wave = tid >> 6;                 // m-quarter index 0..3

    const int b  = blockIdx.x / BLOCKS_PER_BATCH;
    const int n0 = (blockIdx.x % BLOCKS_PER_BATCH) * ROWS_PER_BLOCK;

    const float SCL = 0.25f / 108.0f;

    // ---- per-lane gt state: 4 consecutive m, loaded once per block ----
    const int m0 = wave * 256 + 4 * lane;
    const float* gtb = gt_bboxes + ((size_t)b * MM + m0) * 7;
    const int*   gtl = gt_labels + (size_t)b * MM + m0;

    float gx1[4], gy1[4], gx2[4], gy2[4], areaB[4], bxs[4], bys[4];
    int   lbl4[4];
#pragma unroll
    for (int j = 0; j < 4; ++j) {
        const float* g = gtb + j * 7;
        const float x  = g[0];
        const float y  = g[1];
        const float dx = g[3];
        const float dy = g[4];
        const float x1 = x - 0.5f * dx, x2 = x + 0.5f * dx;
        const float y1 = y - 0.5f * dy, y2 = y + 0.5f * dy;
        gx1[j] = x1; gy1[j] = y1; gx2[j] = x2; gy2[j] = y2;
        areaB[j] = fmaxf(x2 - x1, 0.0f) * fmaxf(y2 - y1, 0.0f);
        bxs[j] = (x + 54.0f) * SCL;
        bys[j] = (y + 54.0f) * SCL;
        lbl4[j] = gtl[j] << 2;
    }

    const int c = (lane < CC) ? lane : 0;
    const float* crow = cls_pred + ((size_t)b * NN + n0) * CC;
    const float* drow = diff + ((size_t)b * NN + n0) * CC;
    const float* rrow = rowbuf + ((size_t)b * NN + n0) * 8;
    const float* arow = bboxes + ((size_t)b * NN + n0) * 7;
    float*       orow = out + ((size_t)b * NN + n0) * MM + m0;

    // ---- row loop ----
#pragma unroll 4
    for (int r = 0; r < ROWS_PER_BLOCK; ++r) {
        float xa1, ya1, xa2, ya2, areaA, axs, ays, dval;
        if (USE_WS) {
            const vfloat4 rA = *reinterpret_cast<const vfloat4*>(rrow + (size_t)r * 8);
            const vfloat4 rB = *reinterpret_cast<const vfloat4*>(rrow + (size_t)r * 8 + 4);
            xa1 = rA.x; ya1 = rA.y; xa2 = rA.z; ya2 = rA.w;
            areaA = rB.x; axs = rB.y; ays = rB.z;
            dval = drow[r * CC + c];
        } else {
            const float* a = arow + r * 7;
            const float ax  = a[0];
            const float ay  = a[1];
            const float adx = a[3];
            const float ady = a[4];
            xa1 = ax - 0.5f * adx; xa2 = ax + 0.5f * adx;
            ya1 = ay - 0.5f * ady; ya2 = ay + 0.5f * ady;
            areaA = fmaxf(xa2 - xa1, 0.0f) * fmaxf(ya2 - ya1, 0.0f);
            axs = (ax + 54.0f) * SCL;
            ays = (ay + 54.0f) * SCL;
            dval = focal_diff(crow[r * CC + c]);
        }

        const int dbits = __float_as_int(dval);

        float vv[4];
#pragma unroll
        for (int j = 0; j < 4; ++j) {
            const float ix1 = fmaxf(xa1, gx1[j]);
            const float iy1 = fmaxf(ya1, gy1[j]);
            const float ix2 = fminf(xa2, gx2[j]);
            const float iy2 = fminf(ya2, gy2[j]);
            const float iw  = fmaxf(ix2 - ix1, 0.0f);
            const float ih  = fmaxf(iy2 - iy1, 0.0f);
            const float inter = iw * ih;
            const float uni   = areaA + areaB[j] - inter;
            const float iou   = inter * fast_rcp(fmaxf(uni, 1e-6f));

            const float cls = __int_as_float(__builtin_amdgcn_ds_bpermute(lbl4[j], dbits));
            const float reg = fabsf(axs - bxs[j]) + fabsf(ays - bys[j]);

            vv[j] = cls + reg - 0.25f * iou;
        }

        // Regular coherent dwordx4 store (nt store broke harness re-poison
        // coherence — r14).
        *reinterpret_cast<vfloat4*>(orow + (size_t)r * MM) =
            (vfloat4){vv[0], vv[1], vv[2], vv[3]};
    }
}

extern "C" void kernel_launch(void* const* d_in, const int* in_sizes, int n_in,
                              void* d_out, int out_size, void* d_ws, size_t ws_size,
                              hipStream_t stream) {
    const float* bboxes    = (const float*)d_in[0];
    const float* gt_bboxes = (const float*)d_in[1];
    const float* cls_pred  = (const float*)d_in[2];
    const int*   gt_labels = (const int*)d_in[3];
    float* out = (float*)d_out;

    const int grid = BB * BLOCKS_PER_BATCH;                 // 2048 blocks
    const size_t diff_elems = (size_t)BB * NN * CC;         // 327,680
    const size_t row_elems  = (size_t)BB * NN * 8;          // 262,144
    const size_t need = (diff_elems + row_elems) * sizeof(float);   // ~2.3 MiB

    if (ws_size >= need) {
        float* diff_p = (float*)d_ws;
        float* row_p  = diff_p + diff_elems;
        focal_diff_kernel<<<(int)(diff_elems / 256), 256, 0, stream>>>(cls_pred, diff_p);
        row_pre_kernel<<<(int)((BB * NN) / 256), 256, 0, stream>>>(bboxes, row_p);
        transfusion_cost_kernel<true><<<grid, 256, 0, stream>>>(
            bboxes, gt_bboxes, cls_pred, gt_labels, diff_p, row_p, out);
    } else {
        transfusion_cost_kernel<false><<<grid, 256, 0, stream>>>(
            bboxes, gt_bboxes, cls_pred, gt_labels, nullptr, nullptr, out);
    }
}